// Round 4
// baseline (319.880 us; speedup 1.0000x reference)
//
#include <hip/hip_runtime.h>
#include <stdint.h>

#define KTOT 4507
#define POSTN 1000
#define ATOT 159882
#define NIMG 4
#define CAND_CAP 4096
#define SLOTCAP 5000  // per-image compact capacity (koff spacing = lvl*1000)

// ---------- helpers ----------

__device__ inline unsigned fmono(float f) {
    unsigned u = __float_as_uint(f);
    return (u & 0x80000000u) ? ~u : (u | 0x80000000u);
}
__device__ inline float fmono_inv(unsigned u) {
    unsigned b = (u & 0x80000000u) ? (u ^ 0x80000000u) : ~u;
    return __uint_as_float(b);
}

// exclusive prefix over a 1024-thread block; warpSums = LDS int[>=16]; call uniformly.
__device__ inline int blockExclScan(int v, int* warpSums) {
    int tid = threadIdx.x;
    int lane = tid & 63, wid = tid >> 6;
    int x = v;
#pragma unroll
    for (int d = 1; d < 64; d <<= 1) {
        int y = __shfl_up(x, d);
        if (lane >= d) x += y;
    }
    if (lane == 63) warpSums[wid] = x;
    __syncthreads();
    if (wid == 0) {
        int s = (lane < 16) ? warpSums[lane] : 0;
#pragma unroll
        for (int d = 1; d < 16; d <<= 1) {
            int y = __shfl_up(s, d);
            if (lane >= d) s += y;
        }
        if (lane < 16) warpSums[lane] = s;
    }
    __syncthreads();
    int wpre = (wid == 0) ? 0 : warpSums[wid - 1];
    return wpre + (x - v);
}

// ---------- stage A: per-(img,level) top-k, emitted in (logit desc, idx asc) order ----------

__global__ __launch_bounds__(1024) void topk_kernel(const float* __restrict__ obj,
                                                    int* __restrict__ selIdx,
                                                    float* __restrict__ selLogit) {
    __shared__ unsigned hist[4096];
    __shared__ unsigned long long cand[CAND_CAP];
    __shared__ int s_misc[32];
    __shared__ int s_cnt, s_bstar;

    const int lvlOff[5] = {0, 120000, 150000, 157500, 159375};
    const int lvlN[5]   = {120000, 30000, 7500, 1875, 507};

    int img = blockIdx.x / 5, lvl = blockIdx.x % 5;
    int n = lvlN[lvl];
    int k = (lvl == 4) ? 507 : 1000;
    int koff = lvl * 1000;
    const float* src = obj + (size_t)img * ATOT + lvlOff[lvl];
    int tid = threadIdx.x;
    int lane = tid & 63;

    for (int i = tid; i < 4096; i += 1024) hist[i] = 0u;
    if (tid == 0) s_cnt = 0;
    __syncthreads();

    // pass 1: histogram; 8 named in-flight loads (no arrays -> no spill, pipelined vmcnt)
    for (int base = tid; base < n; base += 8192) {
        float v0 = src[min(base,          n - 1)];
        float v1 = src[min(base + 1024,   n - 1)];
        float v2 = src[min(base + 2048,   n - 1)];
        float v3 = src[min(base + 3072,   n - 1)];
        float v4 = src[min(base + 4096,   n - 1)];
        float v5 = src[min(base + 5120,   n - 1)];
        float v6 = src[min(base + 6144,   n - 1)];
        float v7 = src[min(base + 7168,   n - 1)];
#define HIST1(U, VV) if (base + (U)*1024 < n) atomicAdd(&hist[fmono(VV) >> 20], 1u);
        HIST1(0, v0) HIST1(1, v1) HIST1(2, v2) HIST1(3, v3)
        HIST1(4, v4) HIST1(5, v5) HIST1(6, v6) HIST1(7, v7)
#undef HIST1
    }
    __syncthreads();

    unsigned c0 = hist[4 * tid + 0], c1 = hist[4 * tid + 1];
    unsigned c2 = hist[4 * tid + 2], c3 = hist[4 * tid + 3];
    int mysum = (int)(c0 + c1 + c2 + c3);
    int excl = blockExclScan(mysum, s_misc);
    int target = n - k;
    {
        int P = excl;
        if ((int)c0 > 0 && P <= target && target < P + (int)c0) s_bstar = 4 * tid + 0;
        P += (int)c0;
        if ((int)c1 > 0 && P <= target && target < P + (int)c1) s_bstar = 4 * tid + 1;
        P += (int)c1;
        if ((int)c2 > 0 && P <= target && target < P + (int)c2) s_bstar = 4 * tid + 2;
        P += (int)c2;
        if ((int)c3 > 0 && P <= target && target < P + (int)c3) s_bstar = 4 * tid + 3;
    }
    __syncthreads();
    int bstar = s_bstar;

    // pass 2: gather candidates; named loads + wave-aggregated LDS atomic
    for (int base = tid; base < n; base += 8192) {
        float v0 = src[min(base,          n - 1)];
        float v1 = src[min(base + 1024,   n - 1)];
        float v2 = src[min(base + 2048,   n - 1)];
        float v3 = src[min(base + 3072,   n - 1)];
        float v4 = src[min(base + 4096,   n - 1)];
        float v5 = src[min(base + 5120,   n - 1)];
        float v6 = src[min(base + 6144,   n - 1)];
        float v7 = src[min(base + 7168,   n - 1)];
#define PUSH1(U, VV)                                                                     \
        {                                                                                \
            int ix = base + (U) * 1024;                                                  \
            unsigned key = fmono(VV);                                                    \
            bool s = (ix < n) && ((int)(key >> 20) >= bstar);                            \
            unsigned long long mk = __ballot(s);                                         \
            if (mk) {                                                                    \
                int pre = __popcll(mk & ((1ULL << lane) - 1ULL));                        \
                int ldr = __builtin_ctzll(mk);                                           \
                int basew = 0;                                                           \
                if (lane == ldr) basew = atomicAdd(&s_cnt, __popcll(mk));                \
                basew = __shfl(basew, ldr);                                              \
                if (s) {                                                                 \
                    int pos = basew + pre;                                               \
                    if (pos < CAND_CAP)                                                  \
                        cand[pos] = ((unsigned long long)key << 32) |                    \
                                    (unsigned)(~(unsigned)ix);                           \
                }                                                                        \
            }                                                                            \
        }
        PUSH1(0, v0) PUSH1(1, v1) PUSH1(2, v2) PUSH1(3, v3)
        PUSH1(4, v4) PUSH1(5, v5) PUSH1(6, v6) PUSH1(7, v7)
#undef PUSH1
    }
    __syncthreads();
    int m = s_cnt; if (m > CAND_CAP) m = CAND_CAP;
    for (int i = tid; i < CAND_CAP; i += 1024)
        if (i >= m) cand[i] = 0ULL;
    __syncthreads();

    // bitonic ascending sort of CAND_CAP u64 keys
    for (unsigned kk = 2; kk <= CAND_CAP; kk <<= 1) {
        for (unsigned j = kk >> 1; j > 0; j >>= 1) {
            for (unsigned i = (unsigned)tid; i < CAND_CAP; i += 1024) {
                unsigned ixj = i ^ j;
                if (ixj > i) {
                    unsigned long long a = cand[i], b = cand[ixj];
                    bool up = ((i & kk) == 0);
                    if ((a > b) == up) { cand[i] = b; cand[ixj] = a; }
                }
            }
            __syncthreads();
        }
    }

    for (int r = tid; r < k; r += 1024) {
        unsigned long long key = cand[CAND_CAP - 1 - r];
        unsigned hi = (unsigned)(key >> 32);
        int li = (int)(~(unsigned)key);
        selIdx[(size_t)img * KTOT + koff + r] = lvlOff[lvl] + li;
        selLogit[(size_t)img * KTOT + koff + r] = fmono_inv(hi);
    }
}

// ---------- stage B: decode + score + valid + per-level compaction (fused) ----------

__global__ __launch_bounds__(1024) void decode_compact_kernel(
    const float* __restrict__ deltas, const float* __restrict__ anchors,
    const int* __restrict__ selIdx, const float* __restrict__ selLogit,
    float* __restrict__ sx1, float* __restrict__ sy1, float* __restrict__ sx2,
    float* __restrict__ sy2, float* __restrict__ sscore,
    float* __restrict__ cx1, float* __restrict__ cy1, float* __restrict__ cx2,
    float* __restrict__ cy2, float* __restrict__ car,
    unsigned long long* __restrict__ ckey, int* __restrict__ cslot, int* __restrict__ cm) {
    __shared__ int s_warp[32];
    int img = blockIdx.x / 5, lvl = blockIdx.x % 5;
    int kn = (lvl == 4) ? 507 : 1000;
    int koff = lvl * 1000;
    int tid = threadIdx.x;
    int r = tid;
    size_t o = (size_t)img * KTOT + koff + r;

    float x1 = 0.f, y1 = 0.f, x2 = 0.f, y2 = 0.f, s = 0.f;
    int valid = 0;
    if (r < kn) {
        int idx = selIdx[o];
        float logit = selLogit[o];
        float ef = (float)exp(-(double)logit);
        s = 1.0f / __fadd_rn(1.0f, ef);
        float a0 = anchors[(size_t)idx * 4 + 0], a1 = anchors[(size_t)idx * 4 + 1];
        float a2 = anchors[(size_t)idx * 4 + 2], a3 = anchors[(size_t)idx * 4 + 3];
        const float* dp = deltas + ((size_t)img * ATOT + idx) * 4;
        float dx = dp[0], dy = dp[1];
        const float BCLIP = 4.135166556742356f;  // log(1000/16)
        float dw = fminf(dp[2], BCLIP), dh = fminf(dp[3], BCLIP);
        float wa = __fsub_rn(a2, a0), ha = __fsub_rn(a3, a1);
        float cxa = __fadd_rn(a0, __fmul_rn(0.5f, wa));
        float cya = __fadd_rn(a1, __fmul_rn(0.5f, ha));
        float cx = __fadd_rn(__fmul_rn(dx, wa), cxa);
        float cy = __fadd_rn(__fmul_rn(dy, ha), cya);
        float w = __fmul_rn((float)exp((double)dw), wa);
        float h = __fmul_rn((float)exp((double)dh), ha);
        x1 = __fsub_rn(cx, __fmul_rn(0.5f, w));
        y1 = __fsub_rn(cy, __fmul_rn(0.5f, h));
        x2 = __fadd_rn(cx, __fmul_rn(0.5f, w));
        y2 = __fadd_rn(cy, __fmul_rn(0.5f, h));
        x1 = fminf(fmaxf(x1, 0.0f), 800.0f);
        y1 = fminf(fmaxf(y1, 0.0f), 800.0f);
        x2 = fminf(fmaxf(x2, 0.0f), 800.0f);
        y2 = fminf(fmaxf(y2, 0.0f), 800.0f);
        valid = (__fsub_rn(x2, x1) >= 0.001f) && (__fsub_rn(y2, y1) >= 0.001f) && (s >= 0.0f);
        sx1[o] = x1; sy1[o] = y1; sx2[o] = x2; sy2[o] = y2; sscore[o] = s;
    }

    int pos = blockExclScan(valid, s_warp);
    if (valid) {
        float lf = 1000.0f * (float)lvl;
        size_t cb = (size_t)img * SLOTCAP + koff + pos;
        float ox1 = __fadd_rn(x1, lf);
        float oy1 = __fadd_rn(y1, lf);
        float ox2 = __fadd_rn(x2, lf);
        float oy2 = __fadd_rn(y2, lf);
        cx1[cb] = ox1; cy1[cb] = oy1; cx2[cb] = ox2; cy2[cb] = oy2;
        car[cb] = __fmul_rn(__fsub_rn(ox2, ox1), __fsub_rn(oy2, oy1));
        int p = koff + r;
        ckey[cb] = ((unsigned long long)fmono(s) << 32) | (unsigned)(~(unsigned)p);
        cslot[cb] = p;
    }
    if (tid == 1023) cm[img * 5 + lvl] = pos + valid;
}

// ---------- stage C: suppression-mask build, one wave per 64x64 tile, ballot form ----------

__global__ __launch_bounds__(512) void mask_kernel(
    const float* __restrict__ cx1, const float* __restrict__ cy1,
    const float* __restrict__ cx2, const float* __restrict__ cy2,
    const float* __restrict__ car, const int* __restrict__ cm,
    unsigned long long* __restrict__ maskBuf) {
    __shared__ float lx1[1000], ly1[1000], lx2[1000], ly2[1000], lar[1000];
    int iq = blockIdx.y;
    int img = iq / 5, lvl = iq % 5;
    int m = cm[img * 5 + lvl];
    int W = (m + 63) >> 6;
    int T = (W * (W + 1)) >> 1;  // one task per lower-triangular 64x64 tile (w, c<=w)
    int tbase = blockIdx.x * 8;
    if (tbase >= T) return;

    size_t cb0 = (size_t)img * SLOTCAP + lvl * 1000;
    for (int q = threadIdx.x; q < m; q += 512) {
        lx1[q] = cx1[cb0 + q]; ly1[q] = cy1[cb0 + q];
        lx2[q] = cx2[cb0 + q]; ly2[q] = cy2[cb0 + q];
        lar[q] = car[cb0 + q];
    }
    __syncthreads();

    int wv = threadIdx.x >> 6, lane = threadIdx.x & 63;
    int t = tbase + wv;
    if (t >= T) return;
    int w = (int)((sqrtf(8.0f * (float)t + 1.0f) - 1.0f) * 0.5f);
    while (((w + 1) * (w + 2)) / 2 <= t) w++;
    while ((w * (w + 1)) / 2 > t) w--;
    int c = t - ((w * (w + 1)) >> 1);

    size_t mOff = (size_t)img * 68056 + (size_t)lvl * 16000;
    int Wa = (lvl == 4) ? 8 : 16;
    unsigned long long* M = maskBuf + mOff;

    int j = (w << 6) + lane;
    bool jv = j < m;
    float jx1 = jv ? lx1[j] : 0.f, jy1 = jv ? ly1[j] : 0.f;
    float jx2 = jv ? lx2[j] : 0.f, jy2 = jv ? ly2[j] : 0.f;
    float jar = jv ? lar[j] : 0.f;

    unsigned long long myword = 0ULL;
    int i0 = c << 6, i1 = min(i0 + 64, m);
    for (int i = i0; i < i1; i++) {
        float ix1 = lx1[i], iy1 = ly1[i], ix2 = lx2[i], iy2 = ly2[i], iar = lar[i];
        float ltx = fmaxf(ix1, jx1);
        float lty = fmaxf(iy1, jy1);
        float rbx = fminf(ix2, jx2);
        float rby = fminf(iy2, jy2);
        float wq = fmaxf(__fsub_rn(rbx, ltx), 0.0f);
        float hq = fmaxf(__fsub_rn(rby, lty), 0.0f);
        float inter = __fmul_rn(wq, hq);
        float uni = __fsub_rn(__fadd_rn(iar, jar), inter);
        float iou = inter / uni;  // keep IEEE div: decisions must match reference exactly
        bool bit = jv && (j > i) && (iou > 0.7f);
        unsigned long long bal = __ballot(bit);
        if (lane == (i & 63)) myword = bal;
    }
    int irow = i0 + lane;
    if (irow < i1) M[(size_t)irow * Wa + w] = myword;
}

// ---------- stage D (fused): per-level ballot-scan NMS + global rank + output ----------

__global__ __launch_bounds__(1024) void scanout_kernel(
    const float* __restrict__ sx1, const float* __restrict__ sy1,
    const float* __restrict__ sx2, const float* __restrict__ sy2,
    const float* __restrict__ sscore,
    const unsigned long long* __restrict__ ckey, const int* __restrict__ cslot,
    const int* __restrict__ cm, const unsigned long long* __restrict__ maskBuf,
    float* __restrict__ out) {
    __shared__ int lkeep[5][1024];
    __shared__ unsigned long long kkey[SLOTCAP];
    __shared__ int kslot[SLOTCAP];
    __shared__ int s_warp[32];
    __shared__ int s_cnt[5];

    int img = blockIdx.x, tid = threadIdx.x;
    int wv = tid >> 6, lane = tid & 63;

    // waves 0..4 each run their level's sequential greedy scan.
    // Depth-16 software pipeline with NAMED u64 prefetch registers (no arrays ->
    // no spill -> fine-grained vmcnt, 16 loads in flight).
    if (wv < 5) {
        int lvl = wv;
        int m = cm[img * 5 + lvl];
        int W = (m + 63) >> 6;
        int Wa = (lvl == 4) ? 8 : 16;
        const unsigned long long* M = maskBuf + (size_t)img * 68056 + (size_t)lvl * 16000;
        bool own = lane < W;
        int mlim = min(m, (lane + 1) << 6);  // rows >= mlim have zero bits in word `lane`
        const unsigned long long* Mr = M + lane;
        unsigned long long remv = 0ULL;

#define LROW(ROW) ((own && (ROW) < mlim) ? Mr[(size_t)(ROW) * Wa] : 0ULL)
        unsigned long long q0 = LROW(0), q1 = LROW(1), q2 = LROW(2), q3 = LROW(3);
        unsigned long long q4 = LROW(4), q5 = LROW(5), q6 = LROW(6), q7 = LROW(7);
        unsigned long long q8 = LROW(8), q9 = LROW(9), q10 = LROW(10), q11 = LROW(11);
        unsigned long long q12 = LROW(12), q13 = LROW(13), q14 = LROW(14), q15 = LROW(15);

#define STEP(Q, IDX)                                                                     \
        {                                                                                \
            int i_ = (IDX);                                                              \
            if (i_ < m) {                                                                \
                bool mine = ((remv >> (i_ & 63)) & 1ULL) != 0ULL;                        \
                unsigned long long bal = __ballot(mine);                                 \
                bool alive = ((bal >> (i_ >> 6)) & 1ULL) == 0ULL;                        \
                if (alive) remv |= (Q);                                                  \
                if (lane == 0) lkeep[lvl][i_] = alive ? 1 : 0;                           \
            }                                                                            \
            (Q) = LROW(i_ + 16);                                                         \
        }
        for (int base = 0; base < m; base += 16) {
            STEP(q0, base + 0)  STEP(q1, base + 1)  STEP(q2, base + 2)  STEP(q3, base + 3)
            STEP(q4, base + 4)  STEP(q5, base + 5)  STEP(q6, base + 6)  STEP(q7, base + 7)
            STEP(q8, base + 8)  STEP(q9, base + 9)  STEP(q10, base + 10) STEP(q11, base + 11)
            STEP(q12, base + 12) STEP(q13, base + 13) STEP(q14, base + 14) STEP(q15, base + 15)
        }
#undef STEP
#undef LROW
    }
    __syncthreads();

    // per-level stable compaction of keeps into LDS kept lists
    for (int lvl = 0; lvl < 5; lvl++) {
        int m = cm[img * 5 + lvl];
        int koff = lvl * 1000;
        int flag = (tid < m) ? lkeep[lvl][tid] : 0;
        int pos = blockExclScan(flag, s_warp);
        if (flag) {
            size_t cb = (size_t)img * SLOTCAP + koff + tid;
            kkey[koff + pos] = ckey[cb];
            kslot[koff + pos] = cslot[cb];
        }
        if (tid == 1023) s_cnt[lvl] = pos + flag;
        __syncthreads();
    }

    int tK = s_cnt[0] + s_cnt[1] + s_cnt[2] + s_cnt[3] + s_cnt[4];

    // global rank via 5-list binary search; write output rows
    for (int lvl = 0; lvl < 5; lvl++) {
        int Kc = s_cnt[lvl];
        int koff = lvl * 1000;
        for (int q = tid; q < Kc; q += 1024) {
            unsigned long long key = kkey[koff + q];
            int rank = q;  // own list: q keys strictly greater (desc, distinct)
#pragma unroll
            for (int ol = 0; ol < 5; ol++) {
                if (ol == lvl) continue;
                int lo = 0, hi = s_cnt[ol], base = ol * 1000;
                while (lo < hi) {
                    int mid = (lo + hi) >> 1;
                    if (kkey[base + mid] > key) lo = mid + 1; else hi = mid;
                }
                rank += lo;
            }
            if (rank < POSTN) {
                int slot = kslot[koff + q];
                size_t o = (size_t)img * KTOT + slot;
                float* dst = out + ((size_t)img * POSTN + rank) * 5;
                dst[0] = sx1[o]; dst[1] = sy1[o]; dst[2] = sx2[o]; dst[3] = sy2[o];
                dst[4] = sscore[o];
            }
        }
    }

    int z0 = tK < POSTN ? tK : POSTN;
    int nz = (POSTN - z0) * 5;
    float* ob = out + (size_t)img * POSTN * 5 + (size_t)z0 * 5;
    for (int u = tid; u < nz; u += 1024) ob[u] = 0.f;
}

// ---------- host ----------

extern "C" void kernel_launch(void* const* d_in, const int* in_sizes, int n_in,
                              void* d_out, int out_size, void* d_ws, size_t ws_size,
                              hipStream_t stream) {
    const float* obj = (const float*)d_in[0];
    const float* deltas = (const float*)d_in[1];
    const float* anchors = (const float*)d_in[2];
    float* out = (float*)d_out;

    char* ws = (char*)d_ws;
    size_t off = 0;
    auto alloc = [&](size_t bytes) {
        size_t o = off;
        off += (bytes + 255) & ~(size_t)255;
        return o;
    };
    int* selIdx = (int*)(ws + alloc((size_t)NIMG * KTOT * 4));
    float* selLogit = (float*)(ws + alloc((size_t)NIMG * KTOT * 4));
    float* sx1 = (float*)(ws + alloc((size_t)NIMG * KTOT * 4));
    float* sy1 = (float*)(ws + alloc((size_t)NIMG * KTOT * 4));
    float* sx2 = (float*)(ws + alloc((size_t)NIMG * KTOT * 4));
    float* sy2 = (float*)(ws + alloc((size_t)NIMG * KTOT * 4));
    float* sscore = (float*)(ws + alloc((size_t)NIMG * KTOT * 4));
    float* cx1 = (float*)(ws + alloc((size_t)NIMG * SLOTCAP * 4));
    float* cy1 = (float*)(ws + alloc((size_t)NIMG * SLOTCAP * 4));
    float* cx2 = (float*)(ws + alloc((size_t)NIMG * SLOTCAP * 4));
    float* cy2 = (float*)(ws + alloc((size_t)NIMG * SLOTCAP * 4));
    float* car = (float*)(ws + alloc((size_t)NIMG * SLOTCAP * 4));
    unsigned long long* ckey = (unsigned long long*)(ws + alloc((size_t)NIMG * SLOTCAP * 8));
    int* cslot = (int*)(ws + alloc((size_t)NIMG * SLOTCAP * 4));
    int* cm = (int*)(ws + alloc((size_t)NIMG * 5 * 4));
    unsigned long long* maskBuf = (unsigned long long*)(ws + alloc((size_t)NIMG * 68056ULL * 8));

    topk_kernel<<<dim3(NIMG * 5), dim3(1024), 0, stream>>>(obj, selIdx, selLogit);
    decode_compact_kernel<<<dim3(NIMG * 5), dim3(1024), 0, stream>>>(
        deltas, anchors, selIdx, selLogit, sx1, sy1, sx2, sy2, sscore,
        cx1, cy1, cx2, cy2, car, ckey, cslot, cm);
    mask_kernel<<<dim3(17, NIMG * 5), dim3(512), 0, stream>>>(cx1, cy1, cx2, cy2, car, cm,
                                                              maskBuf);
    scanout_kernel<<<dim3(NIMG), dim3(1024), 0, stream>>>(
        sx1, sy1, sx2, sy2, sscore, ckey, cslot, cm, maskBuf, out);
}

// Round 5
// 290.331 us; speedup vs baseline: 1.1018x; 1.1018x over previous
//
#include <hip/hip_runtime.h>
#include <stdint.h>

#define KTOT 4507
#define POSTN 1000
#define ATOT 159882
#define NIMG 4
#define CAND_CAP 4096
#define SLOTCAP 5000  // per-image compact capacity (koff spacing = lvl*1000)
#define CHUNK 256     // rows per staged scan chunk

// ---------- helpers ----------

__device__ inline unsigned fmono(float f) {
    unsigned u = __float_as_uint(f);
    return (u & 0x80000000u) ? ~u : (u | 0x80000000u);
}
__device__ inline float fmono_inv(unsigned u) {
    unsigned b = (u & 0x80000000u) ? (u ^ 0x80000000u) : ~u;
    return __uint_as_float(b);
}

// exclusive prefix over a 1024-thread block; warpSums = LDS int[>=16]; call uniformly.
__device__ inline int blockExclScan(int v, int* warpSums) {
    int tid = threadIdx.x;
    int lane = tid & 63, wid = tid >> 6;
    int x = v;
#pragma unroll
    for (int d = 1; d < 64; d <<= 1) {
        int y = __shfl_up(x, d);
        if (lane >= d) x += y;
    }
    if (lane == 63) warpSums[wid] = x;
    __syncthreads();
    if (wid == 0) {
        int s = (lane < 16) ? warpSums[lane] : 0;
#pragma unroll
        for (int d = 1; d < 16; d <<= 1) {
            int y = __shfl_up(s, d);
            if (lane >= d) s += y;
        }
        if (lane < 16) warpSums[lane] = s;
    }
    __syncthreads();
    int wpre = (wid == 0) ? 0 : warpSums[wid - 1];
    return wpre + (x - v);
}

// ---------- stage A: per-(img,level) top-k, emitted in (logit desc, idx asc) order ----------

__global__ __launch_bounds__(1024) void topk_kernel(const float* __restrict__ obj,
                                                    int* __restrict__ selIdx,
                                                    float* __restrict__ selLogit) {
    __shared__ unsigned hist[4096];
    __shared__ unsigned long long cand[CAND_CAP];
    __shared__ int s_misc[32];
    __shared__ int s_cnt, s_bstar;

    const int lvlOff[5] = {0, 120000, 150000, 157500, 159375};
    const int lvlN[5]   = {120000, 30000, 7500, 1875, 507};

    int img = blockIdx.x / 5, lvl = blockIdx.x % 5;
    int n = lvlN[lvl];
    int k = (lvl == 4) ? 507 : 1000;
    int koff = lvl * 1000;
    const float* src = obj + (size_t)img * ATOT + lvlOff[lvl];
    int tid = threadIdx.x;
    int lane = tid & 63;

    for (int i = tid; i < 4096; i += 1024) hist[i] = 0u;
    if (tid == 0) s_cnt = 0;
    __syncthreads();

    // pass 1: histogram; 8 named in-flight loads
    for (int base = tid; base < n; base += 8192) {
        float v0 = src[min(base,          n - 1)];
        float v1 = src[min(base + 1024,   n - 1)];
        float v2 = src[min(base + 2048,   n - 1)];
        float v3 = src[min(base + 3072,   n - 1)];
        float v4 = src[min(base + 4096,   n - 1)];
        float v5 = src[min(base + 5120,   n - 1)];
        float v6 = src[min(base + 6144,   n - 1)];
        float v7 = src[min(base + 7168,   n - 1)];
#define HIST1(U, VV) if (base + (U)*1024 < n) atomicAdd(&hist[fmono(VV) >> 20], 1u);
        HIST1(0, v0) HIST1(1, v1) HIST1(2, v2) HIST1(3, v3)
        HIST1(4, v4) HIST1(5, v5) HIST1(6, v6) HIST1(7, v7)
#undef HIST1
    }
    __syncthreads();

    unsigned c0 = hist[4 * tid + 0], c1 = hist[4 * tid + 1];
    unsigned c2 = hist[4 * tid + 2], c3 = hist[4 * tid + 3];
    int mysum = (int)(c0 + c1 + c2 + c3);
    int excl = blockExclScan(mysum, s_misc);
    int target = n - k;
    {
        int P = excl;
        if ((int)c0 > 0 && P <= target && target < P + (int)c0) s_bstar = 4 * tid + 0;
        P += (int)c0;
        if ((int)c1 > 0 && P <= target && target < P + (int)c1) s_bstar = 4 * tid + 1;
        P += (int)c1;
        if ((int)c2 > 0 && P <= target && target < P + (int)c2) s_bstar = 4 * tid + 2;
        P += (int)c2;
        if ((int)c3 > 0 && P <= target && target < P + (int)c3) s_bstar = 4 * tid + 3;
    }
    __syncthreads();
    int bstar = s_bstar;

    // pass 2: gather candidates; named loads + wave-aggregated LDS atomic
    for (int base = tid; base < n; base += 8192) {
        float v0 = src[min(base,          n - 1)];
        float v1 = src[min(base + 1024,   n - 1)];
        float v2 = src[min(base + 2048,   n - 1)];
        float v3 = src[min(base + 3072,   n - 1)];
        float v4 = src[min(base + 4096,   n - 1)];
        float v5 = src[min(base + 5120,   n - 1)];
        float v6 = src[min(base + 6144,   n - 1)];
        float v7 = src[min(base + 7168,   n - 1)];
#define PUSH1(U, VV)                                                                     \
        {                                                                                \
            int ix = base + (U) * 1024;                                                  \
            unsigned key = fmono(VV);                                                    \
            bool s = (ix < n) && ((int)(key >> 20) >= bstar);                            \
            unsigned long long mk = __ballot(s);                                         \
            if (mk) {                                                                    \
                int pre = __popcll(mk & ((1ULL << lane) - 1ULL));                        \
                int ldr = __builtin_ctzll(mk);                                           \
                int basew = 0;                                                           \
                if (lane == ldr) basew = atomicAdd(&s_cnt, __popcll(mk));                \
                basew = __shfl(basew, ldr);                                              \
                if (s) {                                                                 \
                    int pos = basew + pre;                                               \
                    if (pos < CAND_CAP)                                                  \
                        cand[pos] = ((unsigned long long)key << 32) |                    \
                                    (unsigned)(~(unsigned)ix);                           \
                }                                                                        \
            }                                                                            \
        }
        PUSH1(0, v0) PUSH1(1, v1) PUSH1(2, v2) PUSH1(3, v3)
        PUSH1(4, v4) PUSH1(5, v5) PUSH1(6, v6) PUSH1(7, v7)
#undef PUSH1
    }
    __syncthreads();
    int m = s_cnt; if (m > CAND_CAP) m = CAND_CAP;
    for (int i = tid; i < CAND_CAP; i += 1024)
        if (i >= m) cand[i] = 0ULL;
    __syncthreads();

    // bitonic ascending sort of CAND_CAP u64 keys
    for (unsigned kk = 2; kk <= CAND_CAP; kk <<= 1) {
        for (unsigned j = kk >> 1; j > 0; j >>= 1) {
            for (unsigned i = (unsigned)tid; i < CAND_CAP; i += 1024) {
                unsigned ixj = i ^ j;
                if (ixj > i) {
                    unsigned long long a = cand[i], b = cand[ixj];
                    bool up = ((i & kk) == 0);
                    if ((a > b) == up) { cand[i] = b; cand[ixj] = a; }
                }
            }
            __syncthreads();
        }
    }

    for (int r = tid; r < k; r += 1024) {
        unsigned long long key = cand[CAND_CAP - 1 - r];
        unsigned hi = (unsigned)(key >> 32);
        int li = (int)(~(unsigned)key);
        selIdx[(size_t)img * KTOT + koff + r] = lvlOff[lvl] + li;
        selLogit[(size_t)img * KTOT + koff + r] = fmono_inv(hi);
    }
}

// ---------- stage B: decode + score + valid + per-level compaction (fused) ----------

__global__ __launch_bounds__(1024) void decode_compact_kernel(
    const float* __restrict__ deltas, const float* __restrict__ anchors,
    const int* __restrict__ selIdx, const float* __restrict__ selLogit,
    float* __restrict__ sx1, float* __restrict__ sy1, float* __restrict__ sx2,
    float* __restrict__ sy2, float* __restrict__ sscore,
    float* __restrict__ cx1, float* __restrict__ cy1, float* __restrict__ cx2,
    float* __restrict__ cy2, float* __restrict__ car,
    unsigned long long* __restrict__ ckey, int* __restrict__ cslot, int* __restrict__ cm) {
    __shared__ int s_warp[32];
    int img = blockIdx.x / 5, lvl = blockIdx.x % 5;
    int kn = (lvl == 4) ? 507 : 1000;
    int koff = lvl * 1000;
    int tid = threadIdx.x;
    int r = tid;
    size_t o = (size_t)img * KTOT + koff + r;

    float x1 = 0.f, y1 = 0.f, x2 = 0.f, y2 = 0.f, s = 0.f;
    int valid = 0;
    if (r < kn) {
        int idx = selIdx[o];
        float logit = selLogit[o];
        float ef = (float)exp(-(double)logit);
        s = 1.0f / __fadd_rn(1.0f, ef);
        float a0 = anchors[(size_t)idx * 4 + 0], a1 = anchors[(size_t)idx * 4 + 1];
        float a2 = anchors[(size_t)idx * 4 + 2], a3 = anchors[(size_t)idx * 4 + 3];
        const float* dp = deltas + ((size_t)img * ATOT + idx) * 4;
        float dx = dp[0], dy = dp[1];
        const float BCLIP = 4.135166556742356f;  // log(1000/16)
        float dw = fminf(dp[2], BCLIP), dh = fminf(dp[3], BCLIP);
        float wa = __fsub_rn(a2, a0), ha = __fsub_rn(a3, a1);
        float cxa = __fadd_rn(a0, __fmul_rn(0.5f, wa));
        float cya = __fadd_rn(a1, __fmul_rn(0.5f, ha));
        float cx = __fadd_rn(__fmul_rn(dx, wa), cxa);
        float cy = __fadd_rn(__fmul_rn(dy, ha), cya);
        float w = __fmul_rn((float)exp((double)dw), wa);
        float h = __fmul_rn((float)exp((double)dh), ha);
        x1 = __fsub_rn(cx, __fmul_rn(0.5f, w));
        y1 = __fsub_rn(cy, __fmul_rn(0.5f, h));
        x2 = __fadd_rn(cx, __fmul_rn(0.5f, w));
        y2 = __fadd_rn(cy, __fmul_rn(0.5f, h));
        x1 = fminf(fmaxf(x1, 0.0f), 800.0f);
        y1 = fminf(fmaxf(y1, 0.0f), 800.0f);
        x2 = fminf(fmaxf(x2, 0.0f), 800.0f);
        y2 = fminf(fmaxf(y2, 0.0f), 800.0f);
        valid = (__fsub_rn(x2, x1) >= 0.001f) && (__fsub_rn(y2, y1) >= 0.001f) && (s >= 0.0f);
        sx1[o] = x1; sy1[o] = y1; sx2[o] = x2; sy2[o] = y2; sscore[o] = s;
    }

    int pos = blockExclScan(valid, s_warp);
    if (valid) {
        float lf = 1000.0f * (float)lvl;
        size_t cb = (size_t)img * SLOTCAP + koff + pos;
        float ox1 = __fadd_rn(x1, lf);
        float oy1 = __fadd_rn(y1, lf);
        float ox2 = __fadd_rn(x2, lf);
        float oy2 = __fadd_rn(y2, lf);
        cx1[cb] = ox1; cy1[cb] = oy1; cx2[cb] = ox2; cy2[cb] = oy2;
        car[cb] = __fmul_rn(__fsub_rn(ox2, ox1), __fsub_rn(oy2, oy1));
        int p = koff + r;
        ckey[cb] = ((unsigned long long)fmono(s) << 32) | (unsigned)(~(unsigned)p);
        cslot[cb] = p;
    }
    if (tid == 1023) cm[img * 5 + lvl] = pos + valid;
}

// ---------- stage C: suppression-mask build, one wave per 64x64 tile, ballot form ----------

__global__ __launch_bounds__(512) void mask_kernel(
    const float* __restrict__ cx1, const float* __restrict__ cy1,
    const float* __restrict__ cx2, const float* __restrict__ cy2,
    const float* __restrict__ car, const int* __restrict__ cm,
    unsigned long long* __restrict__ maskBuf) {
    __shared__ float lx1[1000], ly1[1000], lx2[1000], ly2[1000], lar[1000];
    int iq = blockIdx.y;
    int img = iq / 5, lvl = iq % 5;
    int m = cm[img * 5 + lvl];
    int W = (m + 63) >> 6;
    int T = (W * (W + 1)) >> 1;  // one task per lower-triangular 64x64 tile (w, c<=w)
    int tbase = blockIdx.x * 8;
    if (tbase >= T) return;

    size_t cb0 = (size_t)img * SLOTCAP + lvl * 1000;
    for (int q = threadIdx.x; q < m; q += 512) {
        lx1[q] = cx1[cb0 + q]; ly1[q] = cy1[cb0 + q];
        lx2[q] = cx2[cb0 + q]; ly2[q] = cy2[cb0 + q];
        lar[q] = car[cb0 + q];
    }
    __syncthreads();

    int wv = threadIdx.x >> 6, lane = threadIdx.x & 63;
    int t = tbase + wv;
    if (t >= T) return;
    int w = (int)((sqrtf(8.0f * (float)t + 1.0f) - 1.0f) * 0.5f);
    while (((w + 1) * (w + 2)) / 2 <= t) w++;
    while ((w * (w + 1)) / 2 > t) w--;
    int c = t - ((w * (w + 1)) >> 1);

    size_t mOff = (size_t)img * 68056 + (size_t)lvl * 16000;
    int Wa = (lvl == 4) ? 8 : 16;
    unsigned long long* M = maskBuf + mOff;

    int j = (w << 6) + lane;
    bool jv = j < m;
    float jx1 = jv ? lx1[j] : 0.f, jy1 = jv ? ly1[j] : 0.f;
    float jx2 = jv ? lx2[j] : 0.f, jy2 = jv ? ly2[j] : 0.f;
    float jar = jv ? lar[j] : 0.f;

    unsigned long long myword = 0ULL;
    int i0 = c << 6, i1 = min(i0 + 64, m);
    for (int i = i0; i < i1; i++) {
        float ix1 = lx1[i], iy1 = ly1[i], ix2 = lx2[i], iy2 = ly2[i], iar = lar[i];
        float ltx = fmaxf(ix1, jx1);
        float lty = fmaxf(iy1, jy1);
        float rbx = fminf(ix2, jx2);
        float rby = fminf(iy2, jy2);
        float wq = fmaxf(__fsub_rn(rbx, ltx), 0.0f);
        float hq = fmaxf(__fsub_rn(rby, lty), 0.0f);
        float inter = __fmul_rn(wq, hq);
        float uni = __fsub_rn(__fadd_rn(iar, jar), inter);
        float iou = inter / uni;  // keep IEEE div: decisions must match reference exactly
        bool bit = jv && (j > i) && (iou > 0.7f);
        unsigned long long bal = __ballot(bit);
        if (lane == (i & 63)) myword = bal;
    }
    int irow = i0 + lane;
    if (irow < i1) M[(size_t)irow * Wa + w] = myword;
}

// ---------- stage C2: greedy scan, LDS-staged (wave 0 scans, waves 1-3 prefetch) ----------

__global__ __launch_bounds__(256, 1) void scan_kernel(
    const unsigned long long* __restrict__ maskBuf, const int* __restrict__ cm,
    unsigned long long* __restrict__ keepWords) {
    __shared__ unsigned long long sbuf[2][CHUNK * 16];  // 64 KB double buffer
    int img = blockIdx.x / 5, lvl = blockIdx.x % 5;
    int m = cm[img * 5 + lvl];
    int W = (m + 63) >> 6;
    int Wa = (lvl == 4) ? 8 : 16;
    const unsigned long long* M = maskBuf + (size_t)img * 68056 + (size_t)lvl * 16000;
    int tid = threadIdx.x;
    int wv = tid >> 6, lane = tid & 63;
    int nch = (m + CHUNK - 1) / CHUNK;

    // stage chunk 0 (whole block, coalesced)
    {
        int words0 = min(CHUNK, m) * Wa;
        for (int u = tid; u < words0; u += 256) sbuf[0][u] = M[u];
    }
    __syncthreads();

    unsigned long long remv = 0ULL;  // wave 0, lane l: removal word l
    unsigned long long kw = 0ULL;    // wave 0, lane l: keep bits for rows [l*64, l*64+64)

    for (int ch = 0; ch < nch; ch++) {
        if (wv > 0 && ch + 1 < nch) {  // waves 1-3: stage next chunk
            int rbase = (ch + 1) * CHUNK;
            int wordsN = (min(rbase + CHUNK, m) - rbase) * Wa;
            const unsigned long long* srcp = M + (size_t)rbase * Wa;
            unsigned long long* dstp = sbuf[(ch + 1) & 1];
            for (int u = tid - 64; u < wordsN; u += 192) dstp[u] = srcp[u];
        }
        if (wv == 0) {  // wave 0: scan this chunk from LDS
            const unsigned long long* buf = sbuf[ch & 1];
            int i0 = ch * CHUNK, i1 = min(i0 + CHUNK, m);
            bool own = lane < W;
#define LD(ROW) ((own && (ROW) < i1) ? buf[((ROW) - i0) * Wa + lane] : 0ULL)
            unsigned long long p0 = LD(i0 + 0), p1 = LD(i0 + 1), p2 = LD(i0 + 2),
                               p3 = LD(i0 + 3), p4 = LD(i0 + 4), p5 = LD(i0 + 5),
                               p6 = LD(i0 + 6), p7 = LD(i0 + 7);
#define STEP(Q, IDX)                                                                     \
            {                                                                            \
                int i_ = (IDX);                                                          \
                if (i_ < i1) {                                                           \
                    bool mine = ((remv >> (i_ & 63)) & 1ULL) != 0ULL;                    \
                    unsigned long long bal = __ballot(mine);                             \
                    bool alive = ((bal >> (i_ >> 6)) & 1ULL) == 0ULL;                    \
                    if (alive) remv |= (Q);                                              \
                    if ((i_ >> 6) == lane) kw |= (unsigned long long)alive << (i_ & 63); \
                }                                                                        \
                (Q) = LD(i_ + 8);                                                        \
            }
            for (int i = i0; i < i1; i += 8) {
                STEP(p0, i + 0) STEP(p1, i + 1) STEP(p2, i + 2) STEP(p3, i + 3)
                STEP(p4, i + 4) STEP(p5, i + 5) STEP(p6, i + 6) STEP(p7, i + 7)
            }
#undef STEP
#undef LD
        }
        __syncthreads();
    }
    if (wv == 0 && lane < 16) keepWords[(img * 5 + lvl) * 16 + lane] = kw;
}

// ---------- stage D: compaction + global rank + output ----------

__global__ __launch_bounds__(1024) void scanout_kernel(
    const float* __restrict__ sx1, const float* __restrict__ sy1,
    const float* __restrict__ sx2, const float* __restrict__ sy2,
    const float* __restrict__ sscore,
    const unsigned long long* __restrict__ ckey, const int* __restrict__ cslot,
    const int* __restrict__ cm, const unsigned long long* __restrict__ keepWords,
    float* __restrict__ out) {
    __shared__ unsigned long long kkey[SLOTCAP];
    __shared__ int kslot[SLOTCAP];
    __shared__ int s_warp[32];
    __shared__ int s_cnt[5];

    int img = blockIdx.x, tid = threadIdx.x;

    // per-level stable compaction of keeps into LDS kept lists
    for (int lvl = 0; lvl < 5; lvl++) {
        int m = cm[img * 5 + lvl];
        int koff = lvl * 1000;
        int flag = 0;
        if (tid < m)
            flag = (int)((keepWords[(img * 5 + lvl) * 16 + (tid >> 6)] >> (tid & 63)) & 1ULL);
        int pos = blockExclScan(flag, s_warp);
        if (flag) {
            size_t cb = (size_t)img * SLOTCAP + koff + tid;
            kkey[koff + pos] = ckey[cb];
            kslot[koff + pos] = cslot[cb];
        }
        if (tid == 1023) s_cnt[lvl] = pos + flag;
        __syncthreads();
    }

    int tK = s_cnt[0] + s_cnt[1] + s_cnt[2] + s_cnt[3] + s_cnt[4];

    // global rank via 5-list binary search; write output rows
    for (int lvl = 0; lvl < 5; lvl++) {
        int Kc = s_cnt[lvl];
        int koff = lvl * 1000;
        for (int q = tid; q < Kc; q += 1024) {
            unsigned long long key = kkey[koff + q];
            int rank = q;  // own list: q keys strictly greater (desc, distinct)
#pragma unroll
            for (int ol = 0; ol < 5; ol++) {
                if (ol == lvl) continue;
                int lo = 0, hi = s_cnt[ol], base = ol * 1000;
                while (lo < hi) {
                    int mid = (lo + hi) >> 1;
                    if (kkey[base + mid] > key) lo = mid + 1; else hi = mid;
                }
                rank += lo;
            }
            if (rank < POSTN) {
                int slot = kslot[koff + q];
                size_t o = (size_t)img * KTOT + slot;
                float* dst = out + ((size_t)img * POSTN + rank) * 5;
                dst[0] = sx1[o]; dst[1] = sy1[o]; dst[2] = sx2[o]; dst[3] = sy2[o];
                dst[4] = sscore[o];
            }
        }
    }

    int z0 = tK < POSTN ? tK : POSTN;
    int nz = (POSTN - z0) * 5;
    float* ob = out + (size_t)img * POSTN * 5 + (size_t)z0 * 5;
    for (int u = tid; u < nz; u += 1024) ob[u] = 0.f;
}

// ---------- host ----------

extern "C" void kernel_launch(void* const* d_in, const int* in_sizes, int n_in,
                              void* d_out, int out_size, void* d_ws, size_t ws_size,
                              hipStream_t stream) {
    const float* obj = (const float*)d_in[0];
    const float* deltas = (const float*)d_in[1];
    const float* anchors = (const float*)d_in[2];
    float* out = (float*)d_out;

    char* ws = (char*)d_ws;
    size_t off = 0;
    auto alloc = [&](size_t bytes) {
        size_t o = off;
        off += (bytes + 255) & ~(size_t)255;
        return o;
    };
    int* selIdx = (int*)(ws + alloc((size_t)NIMG * KTOT * 4));
    float* selLogit = (float*)(ws + alloc((size_t)NIMG * KTOT * 4));
    float* sx1 = (float*)(ws + alloc((size_t)NIMG * KTOT * 4));
    float* sy1 = (float*)(ws + alloc((size_t)NIMG * KTOT * 4));
    float* sx2 = (float*)(ws + alloc((size_t)NIMG * KTOT * 4));
    float* sy2 = (float*)(ws + alloc((size_t)NIMG * KTOT * 4));
    float* sscore = (float*)(ws + alloc((size_t)NIMG * KTOT * 4));
    float* cx1 = (float*)(ws + alloc((size_t)NIMG * SLOTCAP * 4));
    float* cy1 = (float*)(ws + alloc((size_t)NIMG * SLOTCAP * 4));
    float* cx2 = (float*)(ws + alloc((size_t)NIMG * SLOTCAP * 4));
    float* cy2 = (float*)(ws + alloc((size_t)NIMG * SLOTCAP * 4));
    float* car = (float*)(ws + alloc((size_t)NIMG * SLOTCAP * 4));
    unsigned long long* ckey = (unsigned long long*)(ws + alloc((size_t)NIMG * SLOTCAP * 8));
    int* cslot = (int*)(ws + alloc((size_t)NIMG * SLOTCAP * 4));
    int* cm = (int*)(ws + alloc((size_t)NIMG * 5 * 4));
    unsigned long long* maskBuf = (unsigned long long*)(ws + alloc((size_t)NIMG * 68056ULL * 8));
    unsigned long long* keepWords = (unsigned long long*)(ws + alloc((size_t)NIMG * 5 * 16 * 8));

    topk_kernel<<<dim3(NIMG * 5), dim3(1024), 0, stream>>>(obj, selIdx, selLogit);
    decode_compact_kernel<<<dim3(NIMG * 5), dim3(1024), 0, stream>>>(
        deltas, anchors, selIdx, selLogit, sx1, sy1, sx2, sy2, sscore,
        cx1, cy1, cx2, cy2, car, ckey, cslot, cm);
    mask_kernel<<<dim3(17, NIMG * 5), dim3(512), 0, stream>>>(cx1, cy1, cx2, cy2, car, cm,
                                                              maskBuf);
    scan_kernel<<<dim3(NIMG * 5), dim3(256), 0, stream>>>(maskBuf, cm, keepWords);
    scanout_kernel<<<dim3(NIMG), dim3(1024), 0, stream>>>(
        sx1, sy1, sx2, sy2, sscore, ckey, cslot, cm, keepWords, out);
}